// Round 1
// baseline (9507.043 us; speedup 1.0000x reference)
//
#include <hip/hip_runtime.h>
#include <math.h>

#define NB 8192
#define DK 128
#define TILE 64
#define SPLITJ 4
#define ASTR 132   // A LDS row stride in floats: 528B, 16B aligned, bank-friendly
#define BSTR 68    // B LDS row stride (64-float k-half + pad): 272B, 16B aligned

// ---------------- normalize: one wave per row ----------------
__global__ void norm_kernel(const float* __restrict__ emb, float* __restrict__ xn) {
    int row  = blockIdx.x * 4 + (threadIdx.x >> 6);
    int lane = threadIdx.x & 63;
    float2 v = ((const float2*)(emb + (size_t)row * DK))[lane];
    float ss = v.x * v.x + v.y * v.y;
#pragma unroll
    for (int off = 32; off; off >>= 1) ss += __shfl_xor(ss, off, 64);
    float inv = 1.0f / fmaxf(sqrtf(ss), 1e-12f);
    ((float2*)(xn + (size_t)row * DK))[lane] = make_float2(v.x * inv, v.y * inv);
}

// ---------------- fused gram + hard mining ----------------
// grid: (NB/TILE, SPLITJ); block: 256 threads.
// thread (tx,ty): tx = tid&15 (j dir), ty = tid>>4 (i dir)
// micro-tile: i = i0 + ty*4 + r (r=0..3), j = j0 + tx + 16*c (c=0..3)
__global__ __launch_bounds__(256) void mine_kernel(
    const float* __restrict__ xn, const int* __restrict__ labels,
    const int* __restrict__ groups, float* __restrict__ ap_part,
    float* __restrict__ ansg_part, float* __restrict__ anall_part) {
    __shared__ float As[TILE * ASTR];   // 33792 B
    __shared__ float Bs[TILE * BSTR];   // 17408 B
    __shared__ int   labJ[TILE], grpJ[TILE];

    const int bi = blockIdx.x, part = blockIdx.y;
    const int i0 = bi * TILE;
    const int tid = threadIdx.x;
    const int tx = tid & 15, ty = tid >> 4;

    // stage A tile (row-major, full K)
#pragma unroll
    for (int s = 0; s < 8; s++) {
        int chunk = tid + s * 256;       // 0..2047
        int row = chunk >> 5, k4 = chunk & 31;
        *(float4*)(As + row * ASTR + k4 * 4) =
            *(const float4*)(xn + (size_t)(i0 + row) * DK + k4 * 4);
    }

    int iLab[4], iGrp[4];
#pragma unroll
    for (int r = 0; r < 4; r++) {
        int gi = i0 + ty * 4 + r;
        iLab[r] = labels[gi];
        iGrp[r] = groups[gi];
    }
    float ap[4], ansg[4], anall[4];
#pragma unroll
    for (int r = 0; r < 4; r++) { ap[r] = -1e9f; ansg[r] = 1e9f; anall[r] = 1e9f; }

    const int JSPAN = NB / SPLITJ;       // 2048
    const int jbase = part * JSPAN;

    for (int jt = 0; jt < JSPAN / TILE; jt++) {
        const int j0 = jbase + jt * TILE;
        float acc[4][4] = {};

        // two k-halves of the B tile (keeps LDS under 64 KB static)
#pragma unroll
        for (int h = 0; h < 2; h++) {
            __syncthreads();   // previous consumers of Bs done
#pragma unroll
            for (int s = 0; s < 4; s++) {
                int chunk = tid + s * 256;   // 0..1023
                int row = chunk >> 4, k4 = chunk & 15;
                *(float4*)(Bs + row * BSTR + k4 * 4) =
                    *(const float4*)(xn + (size_t)(j0 + row) * DK + h * 64 + k4 * 4);
            }
            if (h == 0 && tid < TILE) {
                labJ[tid] = labels[j0 + tid];
                grpJ[tid] = groups[j0 + tid];
            }
            __syncthreads();

            const int kb = h * 64;
#pragma unroll
            for (int kk = 0; kk < 64; kk += 4) {
                float4 a4[4], b4[4];
#pragma unroll
                for (int r = 0; r < 4; r++)
                    a4[r] = *(const float4*)(As + (ty * 4 + r) * ASTR + kb + kk);
#pragma unroll
                for (int c = 0; c < 4; c++)
                    b4[c] = *(const float4*)(Bs + (tx + 16 * c) * BSTR + kk);
#pragma unroll
                for (int r = 0; r < 4; r++)
#pragma unroll
                    for (int c = 0; c < 4; c++)
                        acc[r][c] += a4[r].x * b4[c].x + a4[r].y * b4[c].y +
                                     a4[r].z * b4[c].z + a4[r].w * b4[c].w;
            }
        }

        // masked mining epilogue for this tile
#pragma unroll
        for (int c = 0; c < 4; c++) {
            int jl = tx + 16 * c;
            int gj = j0 + jl;
            int lj = labJ[jl], gjv = grpJ[jl];
#pragma unroll
            for (int r = 0; r < 4; r++) {
                int gi = i0 + ty * 4 + r;
                float d = 1.0f - acc[r][c];
                if (iLab[r] == lj) {
                    if (gi != gj) ap[r] = fmaxf(ap[r], d);
                } else {
                    anall[r] = fminf(anall[r], d);
                    if (iGrp[r] == gjv) ansg[r] = fminf(ansg[r], d);
                }
            }
        }
    }

    // reduce across the 16 tx lanes (contiguous lanes within a wave)
#pragma unroll
    for (int r = 0; r < 4; r++) {
#pragma unroll
        for (int off = 8; off; off >>= 1) {
            ap[r]    = fmaxf(ap[r],    __shfl_xor(ap[r],    off, 64));
            ansg[r]  = fminf(ansg[r],  __shfl_xor(ansg[r],  off, 64));
            anall[r] = fminf(anall[r], __shfl_xor(anall[r], off, 64));
        }
    }
    if (tx == 0) {
#pragma unroll
        for (int r = 0; r < 4; r++) {
            int gi = i0 + ty * 4 + r;
            size_t idx = (size_t)part * NB + gi;
            ap_part[idx]    = ap[r];
            ansg_part[idx]  = ansg[r];
            anall_part[idx] = anall[r];
        }
    }
}

// ---------------- combine partials + reduce loss ----------------
__global__ void combine_kernel(const float* __restrict__ ap_part,
                               const float* __restrict__ ansg_part,
                               const float* __restrict__ anall_part,
                               float* __restrict__ accum) {
    int i = blockIdx.x * 256 + threadIdx.x;
    float ap = -1e9f, ansg = 1e9f, anall = 1e9f;
#pragma unroll
    for (int h = 0; h < SPLITJ; h++) {
        size_t idx = (size_t)h * NB + i;
        ap    = fmaxf(ap,    ap_part[idx]);
        ansg  = fminf(ansg,  ansg_part[idx]);
        anall = fminf(anall, anall_part[idx]);
    }
    float an = (ansg < 1e8f) ? ansg : anall;
    float loss = ap - an + 0.1f;
    // sentinels: no-pos -> ap=-1e9 -> loss<0; no-neg -> an=1e9 -> loss<0.
    float inc = (loss > 0.0f) ? 1.0f : 0.0f;
    float val = inc * loss;

    __shared__ float ssum[4], scnt[4];
#pragma unroll
    for (int off = 32; off; off >>= 1) {
        val += __shfl_xor(val, off, 64);
        inc += __shfl_xor(inc, off, 64);
    }
    int wid = threadIdx.x >> 6, lane = threadIdx.x & 63;
    if (lane == 0) { ssum[wid] = val; scnt[wid] = inc; }
    __syncthreads();
    if (threadIdx.x == 0) {
        float s = 0.f, c = 0.f;
#pragma unroll
        for (int w = 0; w < 4; w++) { s += ssum[w]; c += scnt[w]; }
        atomicAdd(&accum[0], s);
        atomicAdd(&accum[1], c);
    }
}

__global__ void finalize_kernel(const float* __restrict__ accum, float* __restrict__ out) {
    float total = accum[0], cnt = accum[1];
    float r = (cnt > 0.0f) ? total / fmaxf(cnt, 1.0f) : 0.0f;
    if (isnan(r)) r = 0.0f;
    out[0] = r;
}

extern "C" void kernel_launch(void* const* d_in, const int* in_sizes, int n_in,
                              void* d_out, int out_size, void* d_ws, size_t ws_size,
                              hipStream_t stream) {
    const float* emb   = (const float*)d_in[0];
    const int* labels  = (const int*)d_in[1];
    const int* groups  = (const int*)d_in[2];
    float* out = (float*)d_out;

    float* xn        = (float*)d_ws;                    // 8192*128 floats = 4 MB
    float* ap_part   = xn + (size_t)NB * DK;
    float* ansg_part = ap_part + (size_t)SPLITJ * NB;
    float* anall_part= ansg_part + (size_t)SPLITJ * NB;
    float* accum     = anall_part + (size_t)SPLITJ * NB; // 2 floats

    hipMemsetAsync(accum, 0, 2 * sizeof(float), stream);
    norm_kernel<<<NB / 4, 256, 0, stream>>>(emb, xn);
    mine_kernel<<<dim3(NB / TILE, SPLITJ), 256, 0, stream>>>(
        xn, labels, groups, ap_part, ansg_part, anall_part);
    combine_kernel<<<NB / 256, 256, 0, stream>>>(ap_part, ansg_part, anall_part, accum);
    finalize_kernel<<<1, 1, 0, stream>>>(accum, out);
}

// Round 2
// 141.546 us; speedup vs baseline: 67.1657x; 67.1657x over previous
//
#include <hip/hip_runtime.h>
#include <math.h>

#define NB 8192
#define DK 128
#define IT 128            // i-tile per block
#define JT 64             // j-tile per staging step
#define SPLITJ 16
#define JSPAN (NB / SPLITJ)   // 512
#define BSTRH 136         // B LDS row stride in bf16 units (272 B; 68 dwords -> conflict-free b128)

typedef __attribute__((ext_vector_type(8))) short short8;
typedef __attribute__((ext_vector_type(16))) float float16;

__device__ inline unsigned short f2bf(float f) {
    unsigned int x = __float_as_uint(f);
    unsigned int r = (x + 0x7fffu + ((x >> 16) & 1u)) >> 16;
    return (unsigned short)r;
}

// ---------------- normalize + convert to bf16: one wave per row ----------------
__global__ void norm_kernel(const float* __restrict__ emb, unsigned short* __restrict__ xnb) {
    int row  = blockIdx.x * 4 + (threadIdx.x >> 6);
    int lane = threadIdx.x & 63;
    float2 v = ((const float2*)(emb + (size_t)row * DK))[lane];
    float ss = v.x * v.x + v.y * v.y;
#pragma unroll
    for (int off = 32; off; off >>= 1) ss += __shfl_xor(ss, off, 64);
    float inv = 1.0f / fmaxf(sqrtf(ss), 1e-12f);
    ushort2 o;
    o.x = f2bf(v.x * inv);
    o.y = f2bf(v.y * inv);
    ((ushort2*)(xnb + (size_t)row * DK))[lane] = o;
}

// ---------------- fused MFMA gram + hard mining ----------------
// grid: (NB/IT, SPLITJ); block: 256 threads = 4 waves.
// Wave w owns i-rows [i0 + w*32, +32). Per j-tile of 64 cols: 2 MFMA col-tiles
// of 32x32, K=128 (8 chained mfma_f32_32x32x16_bf16).
// C layout (verified m74/m101): col = lane&31, row = (reg&3) + 8*(reg>>2) + 4*(lane>>5)
__global__ __launch_bounds__(256) void mine_mfma(
    const unsigned short* __restrict__ xnb, const int* __restrict__ labels,
    const int* __restrict__ groups, float* __restrict__ ap_part,
    float* __restrict__ ansg_part, float* __restrict__ anall_part) {
    __shared__ unsigned short Bs[JT * BSTRH];   // 17408 B
    __shared__ int metaJ[JT];

    const int tid  = threadIdx.x;
    const int w    = tid >> 6;
    const int lane = tid & 63;
    const int half = lane >> 5;
    const int l31  = lane & 31;
    const int i0    = blockIdx.x * IT;
    const int jbase = blockIdx.y * JSPAN;
    const int irow  = i0 + w * 32;   // wave's i-subtile base

    // A fragments for full K=128: element j of short8 = k = ks*16 + half*8 + j
    short8 afrag[8];
#pragma unroll
    for (int ks = 0; ks < 8; ks++)
        afrag[ks] = *(const short8*)(xnb + (size_t)(irow + l31) * DK + ks * 16 + half * 8);

    // per-lane i-row metadata + mining partials (16 C rows per lane)
    int metaI[16];
    float ap[16], ansg[16], anall[16];
#pragma unroll
    for (int reg = 0; reg < 16; reg++) {
        int r  = (reg & 3) + 8 * (reg >> 2) + 4 * half;
        int gi = irow + r;
        metaI[reg] = (labels[gi] << 8) | groups[gi];
        ap[reg] = -1e9f; ansg[reg] = 1e9f; anall[reg] = 1e9f;
    }

    for (int jt = 0; jt < JSPAN / JT; jt++) {
        const int j0 = jbase + jt * JT;
        __syncthreads();   // previous iteration's Bs/metaJ consumers done
#pragma unroll
        for (int s = 0; s < 4; s++) {
            int chunk = tid + s * 256;          // 0..1023
            int row = chunk >> 4, k4 = chunk & 15;
            *(uint4*)&Bs[row * BSTRH + k4 * 8] =
                *(const uint4*)(xnb + (size_t)(j0 + row) * DK + k4 * 8);
        }
        if (tid < JT) metaJ[tid] = (labels[j0 + tid] << 8) | groups[j0 + tid];
        __syncthreads();

#pragma unroll
        for (int ct = 0; ct < 2; ct++) {
            float16 c;
#pragma unroll
            for (int e = 0; e < 16; e++) c[e] = 0.0f;

            const int bro = ct * 32 + l31;      // B row within tile (the C column)
#pragma unroll
            for (int ks = 0; ks < 8; ks++) {
                short8 b = *(const short8*)&Bs[bro * BSTRH + ks * 16 + half * 8];
                c = __builtin_amdgcn_mfma_f32_32x32x16_bf16(afrag[ks], b, c, 0, 0, 0);
            }

            // mining epilogue on the C fragment
            const int gj = j0 + ct * 32 + l31;
            const int mj = metaJ[ct * 32 + l31];
#pragma unroll
            for (int reg = 0; reg < 16; reg++) {
                int r  = (reg & 3) + 8 * (reg >> 2) + 4 * half;
                int gi = irow + r;
                float d = 1.0f - c[reg];
                int x = metaI[reg] ^ mj;
                if ((x & 0x3F00) == 0) {                    // same label
                    if (gi != gj) ap[reg] = fmaxf(ap[reg], d);
                } else {
                    anall[reg] = fminf(anall[reg], d);
                    if ((x & 0xFF) == 0)                    // same group
                        ansg[reg] = fminf(ansg[reg], d);
                }
            }
        }
    }

    // reduce across the 32 column-lanes (stay within the 32-lane half!)
#pragma unroll
    for (int reg = 0; reg < 16; reg++) {
#pragma unroll
        for (int off = 16; off; off >>= 1) {
            ap[reg]    = fmaxf(ap[reg],    __shfl_xor(ap[reg],    off, 64));
            ansg[reg]  = fminf(ansg[reg],  __shfl_xor(ansg[reg],  off, 64));
            anall[reg] = fminf(anall[reg], __shfl_xor(anall[reg], off, 64));
        }
    }
    if (l31 == 0) {
#pragma unroll
        for (int reg = 0; reg < 16; reg++) {
            int r = (reg & 3) + 8 * (reg >> 2) + 4 * half;
            size_t idx = (size_t)blockIdx.y * NB + (irow + r);
            ap_part[idx]    = ap[reg];
            ansg_part[idx]  = ansg[reg];
            anall_part[idx] = anall[reg];
        }
    }
}

// ---------------- combine partials + reduce loss ----------------
__global__ void combine_kernel(const float* __restrict__ ap_part,
                               const float* __restrict__ ansg_part,
                               const float* __restrict__ anall_part,
                               float* __restrict__ accum) {
    int i = blockIdx.x * 256 + threadIdx.x;
    float ap = -1e9f, ansg = 1e9f, anall = 1e9f;
#pragma unroll
    for (int h = 0; h < SPLITJ; h++) {
        size_t idx = (size_t)h * NB + i;
        ap    = fmaxf(ap,    ap_part[idx]);
        ansg  = fminf(ansg,  ansg_part[idx]);
        anall = fminf(anall, anall_part[idx]);
    }
    float an = (ansg < 1e8f) ? ansg : anall;
    float loss = ap - an + 0.1f;
    // sentinels: no-pos -> ap=-1e9 -> loss<0; no-neg -> an=1e9 -> loss<0.
    float inc = (loss > 0.0f) ? 1.0f : 0.0f;
    float val = inc * loss;

    __shared__ float ssum[4], scnt[4];
#pragma unroll
    for (int off = 32; off; off >>= 1) {
        val += __shfl_xor(val, off, 64);
        inc += __shfl_xor(inc, off, 64);
    }
    int wid = threadIdx.x >> 6, lane = threadIdx.x & 63;
    if (lane == 0) { ssum[wid] = val; scnt[wid] = inc; }
    __syncthreads();
    if (threadIdx.x == 0) {
        float s = 0.f, c = 0.f;
#pragma unroll
        for (int wv = 0; wv < 4; wv++) { s += ssum[wv]; c += scnt[wv]; }
        atomicAdd(&accum[0], s);
        atomicAdd(&accum[1], c);
    }
}

__global__ void finalize_kernel(const float* __restrict__ accum, float* __restrict__ out) {
    float total = accum[0], cnt = accum[1];
    float r = (cnt > 0.0f) ? total / fmaxf(cnt, 1.0f) : 0.0f;
    if (isnan(r)) r = 0.0f;
    out[0] = r;
}

extern "C" void kernel_launch(void* const* d_in, const int* in_sizes, int n_in,
                              void* d_out, int out_size, void* d_ws, size_t ws_size,
                              hipStream_t stream) {
    const float* emb  = (const float*)d_in[0];
    const int* labels = (const int*)d_in[1];
    const int* groups = (const int*)d_in[2];
    float* out = (float*)d_out;

    unsigned short* xnb = (unsigned short*)d_ws;            // 8192*128 bf16 = 2 MB
    float* ap_part    = (float*)(xnb + (size_t)NB * DK);
    float* ansg_part  = ap_part + (size_t)SPLITJ * NB;
    float* anall_part = ansg_part + (size_t)SPLITJ * NB;
    float* accum      = anall_part + (size_t)SPLITJ * NB;   // 2 floats

    hipMemsetAsync(accum, 0, 2 * sizeof(float), stream);
    norm_kernel<<<NB / 4, 256, 0, stream>>>(emb, xnb);
    mine_mfma<<<dim3(NB / IT, SPLITJ), 256, 0, stream>>>(
        xnb, labels, groups, ap_part, ansg_part, anall_part);
    combine_kernel<<<NB / 256, 256, 0, stream>>>(ap_part, ansg_part, anall_part, accum);
    finalize_kernel<<<1, 1, 0, stream>>>(accum, out);
}

// Round 3
// 118.388 us; speedup vs baseline: 80.3038x; 1.1956x over previous
//
#include <hip/hip_runtime.h>
#include <math.h>

#define NB 8192
#define DK 128
#define IT 128              // i-rows per block (4 waves x 32)
#define JT 64               // j-cols per LDS tile
#define SPLITJ 16
#define JSPAN (NB / SPLITJ) // 512
#define NT (JSPAN / JT)     // 8 j-tiles per block
#define BSTRH 136           // B LDS row stride in bf16 (272 B) -> conflict-free b128

typedef __attribute__((ext_vector_type(8))) short short8;
typedef __attribute__((ext_vector_type(16))) float float16;

__device__ inline unsigned short f2bf(float f) {
    unsigned int x = __float_as_uint(f);
    unsigned int r = (x + 0x7fffu + ((x >> 16) & 1u)) >> 16;
    return (unsigned short)r;
}

// ---------------- normalize -> bf16, and build packed meta ----------------
__global__ void norm_kernel(const float* __restrict__ emb, const int* __restrict__ labels,
                            const int* __restrict__ groups, unsigned short* __restrict__ xnb,
                            int* __restrict__ meta) {
    int row  = blockIdx.x * 4 + (threadIdx.x >> 6);
    int lane = threadIdx.x & 63;
    float2 v = ((const float2*)(emb + (size_t)row * DK))[lane];
    float ss = v.x * v.x + v.y * v.y;
#pragma unroll
    for (int off = 32; off; off >>= 1) ss += __shfl_xor(ss, off, 64);
    float inv = 1.0f / fmaxf(sqrtf(ss), 1e-12f);
    ushort2 o;
    o.x = f2bf(v.x * inv);
    o.y = f2bf(v.y * inv);
    ((ushort2*)(xnb + (size_t)row * DK))[lane] = o;
    if (lane == 0) meta[row] = (labels[row] << 8) | groups[row];
}

// ---------------- fused MFMA gram + hard mining (similarity space) ----------------
// Partials: apS = MIN similarity over same-label (incl. diag, harmless: s(i,i)~1=max)
//           ansgS/anallS = MAX similarity over (diff-label & same-group) / diff-label.
// C layout (verified): col = lane&31, row = (reg&3) + 8*(reg>>2) + 4*(lane>>5)
__global__ __launch_bounds__(256, 2) void mine_mfma(
    const unsigned short* __restrict__ xnb, const int* __restrict__ meta,
    float* __restrict__ ap_part, float* __restrict__ ansg_part,
    float* __restrict__ anall_part) {
    __shared__ unsigned short Bs[2][JT * BSTRH];   // 2 x 17408 B

    const int tid  = threadIdx.x;
    const int w    = tid >> 6;
    const int lane = tid & 63;
    const int half = lane >> 5;
    const int l31  = lane & 31;
    const int i0    = blockIdx.x * IT;
    const int jbase = blockIdx.y * JSPAN;
    const int irow  = i0 + w * 32;

    // A fragments, full K=128 resident (8 x short8 = 64 VGPRs)
    short8 afrag[8];
#pragma unroll
    for (int ks = 0; ks < 8; ks++)
        afrag[ks] = *(const short8*)(xnb + (size_t)(irow + l31) * DK + ks * 16 + half * 8);

    int metaI[16];
    float apS[16], ansgS[16], anallS[16];
#pragma unroll
    for (int reg = 0; reg < 16; reg++) {
        int r = (reg & 3) + 8 * (reg >> 2) + 4 * half;
        metaI[reg] = meta[irow + r];
        apS[reg] = 1e9f; ansgS[reg] = -1e9f; anallS[reg] = -1e9f;
    }

    // prologue: stage tile 0
#pragma unroll
    for (int s = 0; s < 4; s++) {
        int chunk = tid + s * 256;
        int row = chunk >> 4, k4 = chunk & 15;
        *(uint4*)&Bs[0][row * BSTRH + k4 * 8] =
            *(const uint4*)(xnb + (size_t)(jbase + row) * DK + k4 * 8);
    }
    __syncthreads();

    const float BIG = 1e9f, NEG = -1e9f;

    for (int jt = 0; jt < NT; jt++) {
        const int cur = jt & 1;
        const int j0  = jbase + jt * JT;

        // prefetch next tile into registers (overlaps with compute below)
        uint4 pre[4];
        if (jt + 1 < NT) {
            const int j0n = j0 + JT;
#pragma unroll
            for (int s = 0; s < 4; s++) {
                int chunk = tid + s * 256;
                int row = chunk >> 4, k4 = chunk & 15;
                pre[s] = *(const uint4*)(xnb + (size_t)(j0n + row) * DK + k4 * 8);
            }
        }

        int mjc[2];
        mjc[0] = meta[j0 + l31];
        mjc[1] = meta[j0 + 32 + l31];

#pragma unroll
        for (int ct = 0; ct < 2; ct++) {
            float16 c;
#pragma unroll
            for (int e = 0; e < 16; e++) c[e] = 0.0f;

            const int bro = ct * 32 + l31;
#pragma unroll
            for (int ks = 0; ks < 8; ks++) {
                short8 b = *(const short8*)&Bs[cur][bro * BSTRH + ks * 16 + half * 8];
                c = __builtin_amdgcn_mfma_f32_32x32x16_bf16(afrag[ks], b, c, 0, 0, 0);
            }

            const int mj = mjc[ct];
#pragma unroll
            for (int reg = 0; reg < 16; reg++) {
                float s = c[reg];
                int x = metaI[reg] ^ mj;
                bool sl = (unsigned)x < 0x100u;          // same label
                float selap = sl ? s : BIG;
                apS[reg] = fminf(apS[reg], selap);
                float selna = sl ? NEG : s;              // diff-label ? s : -BIG
                anallS[reg] = fmaxf(anallS[reg], selna);
                bool sg = (x & 0xFF) == 0;               // same group
                float selsg = sg ? selna : NEG;          // diff-label && same-group
                ansgS[reg] = fmaxf(ansgS[reg], selsg);
            }
        }

        // write prefetched tile into the other buffer
        if (jt + 1 < NT) {
#pragma unroll
            for (int s = 0; s < 4; s++) {
                int chunk = tid + s * 256;
                int row = chunk >> 4, k4 = chunk & 15;
                *(uint4*)&Bs[cur ^ 1][row * BSTRH + k4 * 8] = pre[s];
            }
        }
        __syncthreads();
    }

    // butterfly reduce across the 32 column-lanes (offsets < 32 stay in-half)
#pragma unroll
    for (int reg = 0; reg < 16; reg++) {
#pragma unroll
        for (int off = 16; off; off >>= 1) {
            apS[reg]    = fminf(apS[reg],    __shfl_xor(apS[reg],    off, 64));
            ansgS[reg]  = fmaxf(ansgS[reg],  __shfl_xor(ansgS[reg],  off, 64));
            anallS[reg] = fmaxf(anallS[reg], __shfl_xor(anallS[reg], off, 64));
        }
    }
    if (l31 == 0) {
#pragma unroll
        for (int reg = 0; reg < 16; reg++) {
            int r = (reg & 3) + 8 * (reg >> 2) + 4 * half;
            size_t idx = (size_t)blockIdx.y * NB + (irow + r);
            ap_part[idx]    = apS[reg];
            ansg_part[idx]  = ansgS[reg];
            anall_part[idx] = anallS[reg];
        }
    }
}

// ---------------- combine partials -> per-block loss partial sums ----------------
__global__ void combine_kernel(const float* __restrict__ ap_part,
                               const float* __restrict__ ansg_part,
                               const float* __restrict__ anall_part,
                               float* __restrict__ bsum, float* __restrict__ bcnt) {
    int i = blockIdx.x * 256 + threadIdx.x;
    float apS = 1e9f, asg = -1e9f, aall = -1e9f;
#pragma unroll
    for (int h = 0; h < SPLITJ; h++) {
        size_t idx = (size_t)h * NB + i;
        apS  = fminf(apS,  ap_part[idx]);
        asg  = fmaxf(asg,  ansg_part[idx]);
        aall = fmaxf(aall, anall_part[idx]);
    }
    float anS = (asg > -1e8f) ? asg : aall;   // same-group preferred, else any negative
    // loss = dist_ap - dist_an + m = (1-apS) - (1-anS) + m = anS - apS + m
    float loss = anS - apS + 0.1f;
    // sentinels: no-pos -> apS=1e9 -> loss<0; no-neg -> anS=-1e9 -> loss<0.
    float inc = (loss > 0.0f) ? 1.0f : 0.0f;
    float val = inc * loss;

    __shared__ float ssum[4], scnt[4];
#pragma unroll
    for (int off = 32; off; off >>= 1) {
        val += __shfl_xor(val, off, 64);
        inc += __shfl_xor(inc, off, 64);
    }
    int wid = threadIdx.x >> 6, lane = threadIdx.x & 63;
    if (lane == 0) { ssum[wid] = val; scnt[wid] = inc; }
    __syncthreads();
    if (threadIdx.x == 0) {
        float s = 0.f, c = 0.f;
#pragma unroll
        for (int wv = 0; wv < 4; wv++) { s += ssum[wv]; c += scnt[wv]; }
        bsum[blockIdx.x] = s;
        bcnt[blockIdx.x] = c;
    }
}

#define NCOMB (NB / 256)   // 32 combine blocks

__global__ void finalize_kernel(const float* __restrict__ bsum,
                                const float* __restrict__ bcnt,
                                float* __restrict__ out) {
    int lane = threadIdx.x;
    float s = (lane < NCOMB) ? bsum[lane] : 0.0f;
    float c = (lane < NCOMB) ? bcnt[lane] : 0.0f;
#pragma unroll
    for (int off = 32; off; off >>= 1) {
        s += __shfl_xor(s, off, 64);
        c += __shfl_xor(c, off, 64);
    }
    if (lane == 0) {
        float r = (c > 0.0f) ? s / fmaxf(c, 1.0f) : 0.0f;
        if (isnan(r)) r = 0.0f;
        out[0] = r;
    }
}

extern "C" void kernel_launch(void* const* d_in, const int* in_sizes, int n_in,
                              void* d_out, int out_size, void* d_ws, size_t ws_size,
                              hipStream_t stream) {
    const float* emb  = (const float*)d_in[0];
    const int* labels = (const int*)d_in[1];
    const int* groups = (const int*)d_in[2];
    float* out = (float*)d_out;

    unsigned short* xnb = (unsigned short*)d_ws;            // 2 MB
    int*   meta       = (int*)(xnb + (size_t)NB * DK);      // 32 KB
    float* ap_part    = (float*)(meta + NB);
    float* ansg_part  = ap_part + (size_t)SPLITJ * NB;
    float* anall_part = ansg_part + (size_t)SPLITJ * NB;
    float* bsum       = anall_part + (size_t)SPLITJ * NB;
    float* bcnt       = bsum + NCOMB;

    norm_kernel<<<NB / 4, 256, 0, stream>>>(emb, labels, groups, xnb, meta);
    mine_mfma<<<dim3(NB / IT, SPLITJ), 256, 0, stream>>>(
        xnb, meta, ap_part, ansg_part, anall_part);
    combine_kernel<<<NB / 256, 256, 0, stream>>>(ap_part, ansg_part, anall_part, bsum, bcnt);
    finalize_kernel<<<1, 64, 0, stream>>>(bsum, bcnt, out);
}

// Round 4
// 99.091 us; speedup vs baseline: 95.9423x; 1.1947x over previous
//
#include <hip/hip_runtime.h>
#include <math.h>

#define NB 8192
#define DK 128
#define IT 128              // i-rows per block (4 waves x 32)
#define JT 64               // j-cols per LDS tile
#define SPLITJ 16
#define JSPAN (NB / SPLITJ) // 512
#define NT (JSPAN / JT)     // 8 j-tiles per block
#define BSTRH 136           // B LDS row stride in bf16 (272 B) -> conflict-free b128
#define NCOMB (NB / 256)    // 32 combine blocks

typedef __attribute__((ext_vector_type(8))) short short8;
typedef __attribute__((ext_vector_type(16))) float float16;

__device__ inline unsigned short f2bf(float f) {
    unsigned int x = __float_as_uint(f);
    unsigned int r = (x + 0x7fffu + ((x >> 16) & 1u)) >> 16;
    return (unsigned short)r;
}

// ---------------- normalize -> bf16, and build packed meta ----------------
__global__ void norm_kernel(const float* __restrict__ emb, const int* __restrict__ labels,
                            const int* __restrict__ groups, unsigned short* __restrict__ xnb,
                            int* __restrict__ meta) {
    int row  = blockIdx.x * 4 + (threadIdx.x >> 6);
    int lane = threadIdx.x & 63;
    float2 v = ((const float2*)(emb + (size_t)row * DK))[lane];
    float ss = v.x * v.x + v.y * v.y;
#pragma unroll
    for (int off = 32; off; off >>= 1) ss += __shfl_xor(ss, off, 64);
    float inv = 1.0f / fmaxf(sqrtf(ss), 1e-12f);
    ushort2 o;
    o.x = f2bf(v.x * inv);
    o.y = f2bf(v.y * inv);
    ((ushort2*)(xnb + (size_t)row * DK))[lane] = o;
    if (lane == 0) meta[row] = (labels[row] << 8) | groups[row];
}

// ---------------- fused MFMA gram + hard mining (encoded similarity space) ----
// apn = max over all j of ( (same_label? 8:0) - s )   ->  apS = 8 - apn (if apn>2)
// anc = max over all j of ( s - (same_label? 8:0) + (same_group? 4:0) )
//   diff&sg: s+4 in [3,5] ; diff&!sg: s in [-1,1] ; suppressed <= -3.
//   decode: anS = anc>2 ? anc-4 : anc ; has_neg <=> anc > -2.
// C layout (verified): col = lane&31, row = (reg&3) + 8*(reg>>2) + 4*(lane>>5)
__global__ __launch_bounds__(256, 3) void mine_mfma(
    const unsigned short* __restrict__ xnb, const int* __restrict__ meta,
    float* __restrict__ ap_part, float* __restrict__ an_part) {
    __shared__ unsigned short Bs[2][JT * BSTRH];   // 2 x 17408 B

    const int tid  = threadIdx.x;
    const int w    = tid >> 6;
    const int lane = tid & 63;
    const int half = lane >> 5;
    const int l31  = lane & 31;
    const int i0    = blockIdx.x * IT;
    const int jbase = blockIdx.y * JSPAN;
    const int irow  = i0 + w * 32;

    // A fragments, full K=128 resident (8 x short8 = 64 VGPRs)
    short8 afrag[8];
#pragma unroll
    for (int ks = 0; ks < 8; ks++)
        afrag[ks] = *(const short8*)(xnb + (size_t)(irow + l31) * DK + ks * 16 + half * 8);

    int metaI[16];
    float apn[16], anc[16];
#pragma unroll
    for (int reg = 0; reg < 16; reg++) {
        int r = (reg & 3) + 8 * (reg >> 2) + 4 * half;
        metaI[reg] = meta[irow + r];
        apn[reg] = -1e9f; anc[reg] = -1e9f;
    }

    // prologue: stage tile 0
#pragma unroll
    for (int s = 0; s < 4; s++) {
        int chunk = tid + s * 256;
        int row = chunk >> 4, k4 = chunk & 15;
        *(uint4*)&Bs[0][row * BSTRH + k4 * 8] =
            *(const uint4*)(xnb + (size_t)(jbase + row) * DK + k4 * 8);
    }
    __syncthreads();

    for (int jt = 0; jt < NT; jt++) {
        const int cur = jt & 1;
        const int j0  = jbase + jt * JT;

        // prefetch next tile into registers (overlaps with compute below)
        uint4 pre[4];
        if (jt + 1 < NT) {
            const int j0n = j0 + JT;
#pragma unroll
            for (int s = 0; s < 4; s++) {
                int chunk = tid + s * 256;
                int row = chunk >> 4, k4 = chunk & 15;
                pre[s] = *(const uint4*)(xnb + (size_t)(j0n + row) * DK + k4 * 8);
            }
        }

        int mjc[2];
        mjc[0] = meta[j0 + l31];
        mjc[1] = meta[j0 + 32 + l31];

#pragma unroll
        for (int ct = 0; ct < 2; ct++) {
            float16 c;
#pragma unroll
            for (int e = 0; e < 16; e++) c[e] = 0.0f;

            const int bro = ct * 32 + l31;
#pragma unroll
            for (int ks = 0; ks < 8; ks++) {
                short8 b = *(const short8*)&Bs[cur][bro * BSTRH + ks * 16 + half * 8];
                c = __builtin_amdgcn_mfma_f32_32x32x16_bf16(afrag[ks], b, c, 0, 0, 0);
            }

            const int mj = mjc[ct];
#pragma unroll
            for (int reg = 0; reg < 16; reg++) {
                float s = c[reg];
                int x = metaI[reg] ^ mj;
                bool sl = (unsigned)x < 0x100u;     // same label
                float t8 = s - 8.0f;
                float t  = sl ? t8 : s;             // t = s - (sl?8:0)
                apn[reg] = fmaxf(apn[reg], -t);     // neg modifier: free
                bool sg = (x & 0xFFu) == 0u;        // same group
                float t4 = t + 4.0f;
                float v  = sg ? t4 : t;             // + (sg?4:0)
                anc[reg] = fmaxf(anc[reg], v);
            }
        }

        // write prefetched tile into the other buffer
        if (jt + 1 < NT) {
#pragma unroll
            for (int s = 0; s < 4; s++) {
                int chunk = tid + s * 256;
                int row = chunk >> 4, k4 = chunk & 15;
                *(uint4*)&Bs[cur ^ 1][row * BSTRH + k4 * 8] = pre[s];
            }
        }
        __syncthreads();
    }

    // butterfly reduce across the 32 column-lanes (offsets < 32 stay in-half)
#pragma unroll
    for (int reg = 0; reg < 16; reg++) {
#pragma unroll
        for (int off = 16; off; off >>= 1) {
            apn[reg] = fmaxf(apn[reg], __shfl_xor(apn[reg], off, 64));
            anc[reg] = fmaxf(anc[reg], __shfl_xor(anc[reg], off, 64));
        }
    }
    if (l31 == 0) {
#pragma unroll
        for (int reg = 0; reg < 16; reg++) {
            int r = (reg & 3) + 8 * (reg >> 2) + 4 * half;
            size_t idx = (size_t)blockIdx.y * NB + (irow + r);
            ap_part[idx] = apn[reg];
            an_part[idx] = anc[reg];
        }
    }
}

// ---------------- combine partials + ticketed finalize (fused) ----------------
__global__ void combine_kernel(const float* __restrict__ ap_part,
                               const float* __restrict__ an_part,
                               float* __restrict__ accum, int* __restrict__ ticket,
                               float* __restrict__ out) {
    int i = blockIdx.x * 256 + threadIdx.x;
    float apn = -1e9f, anc = -1e9f;
#pragma unroll
    for (int h = 0; h < SPLITJ; h++) {
        size_t idx = (size_t)h * NB + i;
        apn = fmaxf(apn, ap_part[idx]);
        anc = fmaxf(anc, an_part[idx]);
    }
    float anS = (anc > 2.0f) ? anc - 4.0f : anc;
    // loss = anS - (8 - apn) + 0.1 ; sentinels: no-pos apn<=1.02, no-neg anS<=-2.98
    float loss = anS + apn - 7.9f;
    float inc = (loss > 0.0f) ? 1.0f : 0.0f;
    float val = inc * loss;

    __shared__ float ssum[4], scnt[4];
#pragma unroll
    for (int off = 32; off; off >>= 1) {
        val += __shfl_xor(val, off, 64);
        inc += __shfl_xor(inc, off, 64);
    }
    int wid = threadIdx.x >> 6, lane = threadIdx.x & 63;
    if (lane == 0) { ssum[wid] = val; scnt[wid] = inc; }
    __syncthreads();
    if (threadIdx.x == 0) {
        float s = 0.f, c = 0.f;
#pragma unroll
        for (int wv = 0; wv < 4; wv++) { s += ssum[wv]; c += scnt[wv]; }
        atomicAdd(&accum[0], s);
        atomicAdd(&accum[1], c);
        __threadfence();                       // release: accum adds visible device-wide
        int old = atomicAdd(ticket, 1);        // device-scope
        if (old == gridDim.x - 1) {            // last block finalizes
            __threadfence();                   // acquire side
            float total = __hip_atomic_load(&accum[0], __ATOMIC_RELAXED, __HIP_MEMORY_SCOPE_AGENT);
            float cnt   = __hip_atomic_load(&accum[1], __ATOMIC_RELAXED, __HIP_MEMORY_SCOPE_AGENT);
            float r = (cnt > 0.0f) ? total / fmaxf(cnt, 1.0f) : 0.0f;
            if (isnan(r)) r = 0.0f;
            out[0] = r;
        }
    }
}

extern "C" void kernel_launch(void* const* d_in, const int* in_sizes, int n_in,
                              void* d_out, int out_size, void* d_ws, size_t ws_size,
                              hipStream_t stream) {
    const float* emb  = (const float*)d_in[0];
    const int* labels = (const int*)d_in[1];
    const int* groups = (const int*)d_in[2];
    float* out = (float*)d_out;

    unsigned short* xnb = (unsigned short*)d_ws;            // 2 MB
    int*   meta    = (int*)(xnb + (size_t)NB * DK);         // 32 KB
    float* ap_part = (float*)(meta + NB);
    float* an_part = ap_part + (size_t)SPLITJ * NB;
    float* accum   = an_part + (size_t)SPLITJ * NB;         // 2 floats
    int*   ticket  = (int*)(accum + 2);                     // 1 int

    hipMemsetAsync(accum, 0, 3 * sizeof(float), stream);    // accum[0..1] + ticket
    norm_kernel<<<NB / 4, 256, 0, stream>>>(emb, labels, groups, xnb, meta);
    mine_mfma<<<dim3(NB / IT, SPLITJ), 256, 0, stream>>>(
        xnb, meta, ap_part, an_part);
    combine_kernel<<<NCOMB, 256, 0, stream>>>(ap_part, an_part, accum, ticket, out);
}